// Round 21
// baseline (1186.069 us; speedup 1.0000x reference)
//
#include <hip/hip_runtime.h>
#include <hip/hip_bf16.h>

typedef __hip_bfloat16 bf16;
typedef short bf16x8 __attribute__((ext_vector_type(8)));
typedef float f32x4 __attribute__((ext_vector_type(4)));

#define DEV static __device__ __forceinline__

DEV f32x4 fzero4(){ f32x4 z; z[0]=0.f; z[1]=0.f; z[2]=0.f; z[3]=0.f; return z; }

DEV float bf2f(bf16 v){
  unsigned int u = ((unsigned int)*(unsigned short*)&v) << 16;
  return *(float*)&u;
}
DEV float bf2s(short s){
  unsigned int u = ((unsigned int)(unsigned short)s) << 16;
  return *(float*)&u;
}

#if __has_builtin(__builtin_amdgcn_rcpf)
DEV float frcp(float x){ return __builtin_amdgcn_rcpf(x); }
#else
DEV float frcp(float x){ float r; asm("v_rcp_f32 %0, %1" : "=v"(r) : "v"(x)); return r; }
#endif

// fast GELU (tanh form): max abs err ~1e-3 vs exact erf GELU; NaN-safe at |x| large
DEV float fast_gelu(float x){
  float u = 0.7978845608028654f * x * (1.f + 0.044715f * x * x);
  float e = __expf(2.f * u);
  float th = 1.f - 2.f * frcp(e + 1.f);   // tanh(u); e=inf -> 1, e=0 -> -1
  return 0.5f * x * (1.f + th);
}

DEV void gl2lds16(const bf16* g, bf16* l){
  __builtin_amdgcn_global_load_lds(
    (const __attribute__((address_space(1))) void*)g,
    (__attribute__((address_space(3))) void*)l, 16, 0, 0);
}

enum { EP_F32=0, EP_BF16=1, EP_GELU=2, EP_HILO=3, EP_QKV=4, EP_VT=5 };

// C[M][N] = sum_p A_p[M][K] * B_p[N][K]^T  (+bias, epilogue variants)
// BM=NMT*32 (128 or 64), BN=128, BK=32, 256 threads (4 waves).
// 1-D grid = nn * (mchunk*8) blocks; xcd = bid&7 owns m-chunk.
// z-dim batches independent problems: azs/bzs/ozs are element strides; when
// bs1 != null and z>0, bs1 replaces bs0 as the bias (EP_BF16 / EP_HILO).
// Double-buffered LDS staging via global_load_lds: one barrier per K-step.
template<int EPI, int NMT>
__global__ __launch_bounds__(256) void gemm_bt(
    const bf16* A0, const bf16* A1, const bf16* A2,
    const bf16* B0, const bf16* B1, const bf16* B2,
    int npass, int lda, int ldb, int M, int N, int K,
    const float* __restrict__ bs0, const float* __restrict__ bs1, const float* __restrict__ bs2,
    float alpha, void* o0, void* o1, void* o2,
    int nn, int mchunk, int azs, int bzs, int ozs)
{
  constexpr int BM = NMT*32;
  __shared__ __align__(16) bf16 As[2][BM*32];
  __shared__ __align__(16) bf16 Bs[2][128*32];
  const int t = threadIdx.x;
  const int lane = t & 63;
  const int w = t >> 6;
  const int wr = w >> 1, wc = w & 1;
  const int bid = blockIdx.x;
  const int xcd = bid & 7;
  const int idx = bid >> 3;
  const int qm = idx / nn;
  const int mb = xcd*mchunk + qm;
  const int nb = idx - qm*nn;
  const int m0 = mb*BM, n0 = nb*128;
  const int l15 = lane & 15, l4 = lane >> 4;
  const int grow = (lane >> 2);       // 0..15 within a 16-row stripe
  const int gcol = (lane & 3) * 8;    // 0,8,16,24
  const int z = blockIdx.z;
  if (azs){ A0 += (size_t)z*azs; if(A1) A1 += (size_t)z*azs; if(A2) A2 += (size_t)z*azs; }
  if (bzs){ B0 += (size_t)z*bzs; if(B1) B1 += (size_t)z*bzs; if(B2) B2 += (size_t)z*bzs; }

  auto Aof = [&](int p){ return (p==0)?A0:((p==1)?A1:A2); };
  auto Bof = [&](int p){ return (p==0)?B0:((p==1)?B1:B2); };

  auto stageAB = [&](int cb, const bf16* Ag, const bf16* Bg, int k0){
    if constexpr (NMT==4){
      #pragma unroll
      for (int q=0;q<2;q++){
        int row = w*32 + q*16 + grow;
        gl2lds16(Ag + (size_t)(m0+row)*lda + k0 + gcol, As[cb] + (w*32+q*16)*32);
        gl2lds16(Bg + (size_t)(n0+row)*ldb + k0 + gcol, Bs[cb] + (w*32+q*16)*32);
      }
    } else {
      int rA = w*16 + grow;
      gl2lds16(Ag + (size_t)(m0+rA)*lda + k0 + gcol, As[cb] + w*16*32);
      #pragma unroll
      for (int sb=0;sb<2;sb++){
        int rB = (2*w+sb)*16 + grow;
        gl2lds16(Bg + (size_t)(n0+rB)*ldb + k0 + gcol, Bs[cb] + (2*w+sb)*16*32);
      }
    }
  };

  f32x4 acc[NMT][4];
  #pragma unroll
  for (int i=0;i<NMT;i++)
    #pragma unroll
    for (int j=0;j<4;j++) acc[i][j] = fzero4();

  int cur = 0;
  stageAB(0, A0, B0, 0);
  for (int p=0;p<npass;p++){
    for (int k0=0;k0<K;k0+=32){
      __syncthreads();            // buf[cur] staged; prev reads done
      int kn = k0 + 32;
      if (kn < K)            stageAB(cur^1, Aof(p), Bof(p), kn);
      else if (p+1 < npass)  stageAB(cur^1, Aof(p+1), Bof(p+1), 0);
      bf16x8 af[NMT], bfv[4];
      #pragma unroll
      for (int mt=0;mt<NMT;mt++) af[mt] = *(const bf16x8*)(As[cur] + (wr*(NMT*16)+mt*16+l15)*32 + 8*l4);
      #pragma unroll
      for (int nt=0;nt<4;nt++) bfv[nt] = *(const bf16x8*)(Bs[cur] + (wc*64+nt*16+l15)*32 + 8*l4);
      #pragma unroll
      for (int mt=0;mt<NMT;mt++)
        #pragma unroll
        for (int nt=0;nt<4;nt++)
          acc[mt][nt] = __builtin_amdgcn_mfma_f32_16x16x32_bf16(af[mt], bfv[nt], acc[mt][nt], 0, 0, 0);
      cur ^= 1;
    }
  }

  const float* bb = (z && bs1) ? bs1 : bs0;

  #pragma unroll
  for (int mt=0;mt<NMT;mt++){
    #pragma unroll
    for (int nt=0;nt<4;nt++){
      const int crow = m0 + wr*(NMT*16) + mt*16 + l4*4;
      const int ccol = n0 + wc*64 + nt*16 + l15;
      #pragma unroll
      for (int j=0;j<4;j++){
        float v = acc[mt][nt][j];
        int r = crow + j;
        if (EPI==EP_F32){
          float b = bb ? bb[ccol] : 0.f;
          ((float*)o0)[(size_t)r*N + ccol] = alpha*v + b;
        } else if (EPI==EP_BF16){
          float b = bb ? bb[ccol] : 0.f;
          ((bf16*)o0 + (size_t)z*ozs)[(size_t)r*N + ccol] = __float2bfloat16(alpha*v + b);
        } else if (EPI==EP_GELU){
          float xx = v + bb[ccol];
          ((bf16*)o0)[(size_t)r*N + ccol] = __float2bfloat16(fast_gelu(xx));
        } else if (EPI==EP_HILO){
          float xx = (v + bb[ccol]) * alpha;
          bf16 hi = __float2bfloat16(xx);
          ((bf16*)o0 + (size_t)z*ozs)[(size_t)r*N + ccol] = hi;
          ((bf16*)o1 + (size_t)z*ozs)[(size_t)r*N + ccol] = __float2bfloat16(xx - bf2f(hi));
        } else if (EPI==EP_VT){ // v only, transposed [b,h,d,s]; N=512
          int d = ccol;
          int bb2 = r >> 9, s2 = r & 511;
          int hh = d >> 6, dd = d & 63;
          ((bf16*)o2)[(size_t)(((bb2*8)+hh)*64 + dd)*512 + s2] = __float2bfloat16(v + bs2[d]);
        } else { // EP_QKV : N=1536 concat q|k|v; q scaled by alpha; v transposed [b,h,d,s]
          int n = ccol;
          if (n < 512){
            ((bf16*)o0)[(size_t)r*512 + n] = __float2bfloat16((v + bs0[n]) * alpha);
          } else if (n < 1024){
            ((bf16*)o1)[(size_t)r*512 + (n-512)] = __float2bfloat16(v + bs1[n-512]);
          } else {
            int d = n - 1024;
            int bb2 = r >> 9, s2 = r & 511;
            int hh = d >> 6, dd = d & 63;
            ((bf16*)o2)[(size_t)(((bb2*8)+hh)*64 + dd)*512 + s2] = __float2bfloat16(v + bs2[d]);
          }
        }
      }
    }
  }
}

// MFMA flash attention — round-6/15 form (measured best: ~50 us/dispatch).
// 256 thr (4 waves x 16 q-rows), KVBLK=64, single-buffered K/V in LDS (XOR-swizzled),
// SPE (bf16, pre-scaled by 1/sqrt(2dk)) added after the QK MFMAs; __expf softmax;
// unconditional online rescale. 1D grid 1024: h = bid&7 (pins head to XCD).
template<int SPLIT>
__global__ __launch_bounds__(256) void attn_mfma(
  const bf16* __restrict__ Q, const bf16* __restrict__ Qlo,
  const bf16* __restrict__ Kh, const bf16* __restrict__ Klo,
  const bf16* __restrict__ VT, const bf16* __restrict__ SPE,
  bf16* __restrict__ O)
{
  __shared__ __align__(16) bf16 K_lds[64*64];
  __shared__ __align__(16) bf16 V_lds[64*64];
  __shared__ __align__(16) bf16 Klo_lds[SPLIT ? 64*64 : 8];
  __shared__ __align__(16) bf16 P_lds[4][16*64];
  const int t = threadIdx.x;
  const int lane = t & 63, w = t >> 6;
  const int l15 = lane & 15, l4 = lane >> 4;
  const int bid = blockIdx.x;
  const int h = bid & 7;
  const int s2 = bid >> 3;
  const int b = s2 >> 3, qblk = s2 & 7;
  const int q0 = qblk*64 + w*16;
  const float inv_scale = 0.08838834764831845f; // 1/sqrt(128)
  const int xorv = (l15 & 7) << 3;

  bf16x8 qf[2], qflo[2];
  #pragma unroll
  for (int kst=0;kst<2;kst++){
    qf[kst] = *(const bf16x8*)(Q + (size_t)(b*512 + q0 + l15)*512 + h*64 + kst*32 + 8*l4);
    if (SPLIT) qflo[kst] = *(const bf16x8*)(Qlo + (size_t)(b*512 + q0 + l15)*512 + h*64 + kst*32 + 8*l4);
  }
  f32x4 accO[4];
  #pragma unroll
  for (int dt=0;dt<4;dt++) accO[dt] = fzero4();
  float mrow[4], lrow[4];
  #pragma unroll
  for (int j=0;j<4;j++){ mrow[j] = -1e30f; lrow[j] = 0.f; }

  const bf16* spe_h = SPE + (size_t)h*262144;
  const bf16* vbase = VT + (size_t)((b*8)+h)*32768;

  for (int n0=0;n0<512;n0+=64){
    // stage K (and Klo), V^T tiles: wave w covers rows [w*16, w*16+16)
    #pragma unroll
    for (int st=0;st<2;st++){
      int rl = w*16 + st*8 + (lane>>3);          // tile-local row 0..63
      int jj = (lane&7) ^ (rl&7);                // pre-swizzled 16B-chunk col
      gl2lds16(Kh + (size_t)(b*512 + n0 + rl)*512 + h*64 + jj*8, K_lds + (w*16+st*8)*64);
      if (SPLIT)
        gl2lds16(Klo + (size_t)(b*512 + n0 + rl)*512 + h*64 + jj*8, Klo_lds + (w*16+st*8)*64);
      gl2lds16(vbase + (size_t)rl*512 + n0 + jj*8, V_lds + (w*16+st*8)*64);
    }
    __syncthreads();

    f32x4 sc[4];
    #pragma unroll
    for (int c=0;c<4;c++) sc[c] = fzero4();
    #pragma unroll
    for (int c=0;c<4;c++){
      const int rr = c*16 + l15;
      #pragma unroll
      for (int kst=0;kst<2;kst++){
        bf16x8 kf = *(const bf16x8*)(K_lds + rr*64 + ((kst*32 + 8*l4) ^ xorv));
        sc[c] = __builtin_amdgcn_mfma_f32_16x16x32_bf16(qf[kst], kf, sc[c], 0,0,0);
        if (SPLIT){
          sc[c] = __builtin_amdgcn_mfma_f32_16x16x32_bf16(qflo[kst], kf, sc[c], 0,0,0);
          bf16x8 kfl = *(const bf16x8*)(Klo_lds + rr*64 + ((kst*32 + 8*l4) ^ xorv));
          sc[c] = __builtin_amdgcn_mfma_f32_16x16x32_bf16(qf[kst], kfl, sc[c], 0,0,0);
        }
      }
    }
    float sv[4][4];
    #pragma unroll
    for (int c=0;c<4;c++)
      #pragma unroll
      for (int j=0;j<4;j++){
        int qr = q0 + l4*4 + j;
        sv[c][j] = sc[c][j]*inv_scale + bf2f(spe_h[(size_t)qr*512 + n0 + c*16 + l15]);
      }
    float fac[4];
    #pragma unroll
    for (int j=0;j<4;j++){
      float m2 = fmaxf(fmaxf(sv[0][j],sv[1][j]), fmaxf(sv[2][j],sv[3][j]));
      m2 = fmaxf(m2, __shfl_xor(m2,1));
      m2 = fmaxf(m2, __shfl_xor(m2,2));
      m2 = fmaxf(m2, __shfl_xor(m2,4));
      m2 = fmaxf(m2, __shfl_xor(m2,8));
      float mn = fmaxf(mrow[j], m2);
      fac[j] = __expf(mrow[j] - mn);
      mrow[j] = mn;
    }
    #pragma unroll
    for (int j=0;j<4;j++){
      int row = l4*4 + j;
      float ts = 0.f;
      #pragma unroll
      for (int c=0;c<4;c++){
        float pv = __expf(sv[c][j] - mrow[j]);
        ts += pv;
        P_lds[w][row*64 + ((c*16 + l15) ^ ((row&7)<<3))] = __float2bfloat16(pv);
      }
      ts += __shfl_xor(ts,1); ts += __shfl_xor(ts,2);
      ts += __shfl_xor(ts,4); ts += __shfl_xor(ts,8);
      lrow[j] = lrow[j]*fac[j] + ts;
      #pragma unroll
      for (int dt=0;dt<4;dt++) accO[dt][j] *= fac[j];
    }
    #pragma unroll
    for (int kv=0;kv<2;kv++){
      bf16x8 pf = *(const bf16x8*)(P_lds[w] + l15*64 + ((kv*32 + 8*l4) ^ xorv));
      #pragma unroll
      for (int dt=0;dt<4;dt++){
        const int d = dt*16 + l15;
        bf16x8 vf = *(const bf16x8*)(V_lds + d*64 + ((kv*32 + 8*l4) ^ xorv));
        accO[dt] = __builtin_amdgcn_mfma_f32_16x16x32_bf16(pf, vf, accO[dt], 0,0,0);
      }
    }
    __syncthreads();
  }
  float li[4];
  #pragma unroll
  for (int j=0;j<4;j++) li[j] = frcp(lrow[j]);
  #pragma unroll
  for (int dt=0;dt<4;dt++)
    #pragma unroll
    for (int j=0;j<4;j++){
      float v = accO[dt][j] * li[j];
      int r = q0 + l4*4 + j;
      O[(size_t)(b*512+r)*512 + h*64 + dt*16 + l15] = __float2bfloat16(v);
    }
}

// LayerNorm(tmp(bf16) + resid(f32)) -> outf (fp32), outb (bf16). One wave per row.
__global__ __launch_bounds__(256) void ln_kernel(
  const bf16* __restrict__ tmp, const float* __restrict__ resid,
  const float* __restrict__ g, const float* __restrict__ bta,
  float* __restrict__ outf, bf16* __restrict__ outb)
{
  const int row = blockIdx.x*4 + (threadIdx.x>>6);
  const int lane = threadIdx.x & 63;
  const size_t base = (size_t)row*512 + lane*8;
  bf16x8 a = *(const bf16x8*)(tmp+base);
  float4 r0 = *(const float4*)(resid+base), r1 = *(const float4*)(resid+base+4);
  float x[8];
  x[0]=bf2s(a[0])+r0.x; x[1]=bf2s(a[1])+r0.y;
  x[2]=bf2s(a[2])+r0.z; x[3]=bf2s(a[3])+r0.w;
  x[4]=bf2s(a[4])+r1.x; x[5]=bf2s(a[5])+r1.y;
  x[6]=bf2s(a[6])+r1.z; x[7]=bf2s(a[7])+r1.w;
  float s=0.f, sq=0.f;
  #pragma unroll
  for (int i=0;i<8;i++){ s += x[i]; sq += x[i]*x[i]; }
  #pragma unroll
  for (int d=1; d<64; d<<=1){ s += __shfl_xor(s,d); sq += __shfl_xor(sq,d); }
  float mean = s*(1.f/512.f);
  float var = sq*(1.f/512.f) - mean*mean;
  float rr = rsqrtf(var + 1e-6f);
  #pragma unroll
  for (int i=0;i<8;i++){
    int d = lane*8 + i;
    float y = (x[i]-mean)*rr*g[d] + bta[d];
    outf[base+i] = y;
    outb[base+i] = __float2bfloat16(y);
  }
}

// merged transpose+cast for ALL 512x512 weights. grid (16,16,28):
//  z<24: which=z&3 in {Wq,Wk,Wv,Wo}, l=z>>2 -> WqkvT/WoT
//  z=24: peqw->pqwT ; z=25: pekw->pkwT
//  z=26: Wq(l0)->Wq0h+Wq0l ; z=27: Wk(l0)->Wk0h+Wk0l  (hi/lo split)
__global__ __launch_bounds__(256) void tcast_all(
  const float* __restrict__ Wq, const float* __restrict__ Wk,
  const float* __restrict__ Wv, const float* __restrict__ Wo,
  const float* __restrict__ peqw, const float* __restrict__ pekw,
  bf16* __restrict__ WqkvT, bf16* __restrict__ WoT,
  bf16* __restrict__ pqwT, bf16* __restrict__ pkwT,
  bf16* __restrict__ Wq0h, bf16* __restrict__ Wq0l,
  bf16* __restrict__ Wk0h, bf16* __restrict__ Wk0l)
{
  __shared__ float tile[32][33];
  const int z = blockIdx.z;
  const float* src; bf16* dst; bf16* dlo = nullptr;
  if (z < 24){
    int which = z & 3, l = z >> 2;
    src = ((which==0)?Wq:(which==1)?Wk:(which==2)?Wv:Wo) + (size_t)l*262144;
    dst = (which<3) ? (WqkvT + (size_t)l*786432 + (size_t)which*262144)
                    : (WoT + (size_t)l*262144);
  } else if (z==24){ src=peqw; dst=pqwT; }
  else if (z==25){ src=pekw; dst=pkwT; }
  else if (z==26){ src=Wq; dst=Wq0h; dlo=Wq0l; }
  else           { src=Wk; dst=Wk0h; dlo=Wk0l; }

  const int tx = threadIdx.x & 31, ty = threadIdx.x >> 5;
  const int r0 = blockIdx.y*32, c0 = blockIdx.x*32;
  #pragma unroll
  for (int p=0;p<4;p++)
    tile[ty+8*p][tx] = src[(size_t)(r0+ty+8*p)*512 + c0+tx];
  __syncthreads();
  #pragma unroll
  for (int p=0;p<4;p++){
    float v = tile[tx][ty+8*p];
    bf16 hi = __float2bfloat16(v);
    dst[(size_t)(c0+ty+8*p)*512 + r0+tx] = hi;
    if (dlo) dlo[(size_t)(c0+ty+8*p)*512 + r0+tx] = __float2bfloat16(v - bf2f(hi));
  }
}

// transpose + cast fp32 [R][C] -> bf16 [C][R], per grid.z slice (W1/W2 only)
__global__ __launch_bounds__(256) void tcast(
  const float* __restrict__ src, int srcStride,
  bf16* __restrict__ dst, int dstStride,
  int R, int C)
{
  __shared__ float tile[32][33];
  const int z = blockIdx.z;
  src += (size_t)z*srcStride;
  dst += (size_t)z*dstStride;
  const int tx = threadIdx.x & 31, ty = threadIdx.x >> 5;
  const int r0 = blockIdx.y*32, c0 = blockIdx.x*32;
  #pragma unroll
  for (int p=0;p<4;p++)
    tile[ty+8*p][tx] = src[(size_t)(r0+ty+8*p)*C + c0+tx];
  __syncthreads();
  #pragma unroll
  for (int p=0;p<4;p++){
    float v = tile[tx][ty+8*p];
    dst[(size_t)(c0+ty+8*p)*R + r0+tx] = __float2bfloat16(v);
  }
}

// h init (scale + bf16 hi/lo split) fused with pe bf16 cast.
// grid covers 4194304 + 262144 elements.
__global__ void init_h(const float* __restrict__ x, float* __restrict__ hf,
                       bf16* __restrict__ hb, bf16* __restrict__ hlo,
                       const float* __restrict__ pe, bf16* __restrict__ peb){
  int i = blockIdx.x*blockDim.x + threadIdx.x;
  if (i < 4194304){
    float v = x[i]*22.627416997969522f;   // sqrt(512)
    hf[i] = v;
    bf16 hi = __float2bfloat16(v);
    hb[i] = hi;
    hlo[i] = __float2bfloat16(v - bf2f(hi));
  } else if (i < 4456448){
    int j = i - 4194304;
    peb[j] = __float2bfloat16(pe[j]);
  }
}

// pe broadcast chunk of d_out (h chunk is written directly by the last ln_kernel)
__global__ void pe_out(const float* __restrict__ pe, float* __restrict__ out, int n1){
  int i = blockIdx.x*blockDim.x + threadIdx.x;
  if (i < n1) out[n1 + i] = pe[i & 262143];
}

extern "C" void kernel_launch(void* const* d_in, const int* in_sizes, int n_in,
                              void* d_out, int out_size, void* d_ws, size_t ws_size,
                              hipStream_t stream)
{
  const float* x    = (const float*)d_in[0];
  const float* pe   = (const float*)d_in[1];
  const float* peqw = (const float*)d_in[2];
  const float* peqb = (const float*)d_in[3];
  const float* pekw = (const float*)d_in[4];
  const float* pekb = (const float*)d_in[5];
  const float* Wq   = (const float*)d_in[6];
  const float* bq   = (const float*)d_in[7];
  const float* Wk   = (const float*)d_in[8];
  const float* bk   = (const float*)d_in[9];
  const float* Wv   = (const float*)d_in[10];
  const float* bv   = (const float*)d_in[11];
  const float* Wo   = (const float*)d_in[12];
  const float* bo   = (const float*)d_in[13];
  const float* g1   = (const float*)d_in[14];
  const float* bb1  = (const float*)d_in[15];
  const float* W1   = (const float*)d_in[16];
  const float* fb1  = (const float*)d_in[17];
  const float* W2   = (const float*)d_in[18];
  const float* fb2  = (const float*)d_in[19];
  const float* g2   = (const float*)d_in[20];
  const float* bb2  = (const float*)d_in[21];

  char* wp = (char*)d_ws;
  auto carve = [&](size_t bytes)->void*{ void* r = (void*)wp; wp += (bytes + 255) & ~(size_t)255; return r; };
  // persistent fp32 streams
  float* hf   = (float*)carve(16777216);
  float* h1f  = (float*)carve(16777216);
  // region B: tmpb (bf16 8192x512) overlaps qlo|klo (bf16, layer0-attn only)
  char*  regB = (char*)carve(16777216);
  bf16*  tmpb = (bf16*)regB;
  bf16*  qlo  = (bf16*)regB;
  bf16*  klo  = (bf16*)(regB + 8388608);
  // bf16 streams
  bf16* hb    = (bf16*)carve(8388608);
  bf16* hlo   = (bf16*)carve(8388608);
  bf16* h1b   = (bf16*)carve(8388608);
  // region A: gbuf (bf16 8192x2048) overlaps qb|kbuf|vT|obuf (attn phase)
  char* regA  = (char*)carve(33554432);
  bf16* gbuf  = (bf16*)regA;
  bf16* qb    = (bf16*)regA;
  bf16* kbuf  = (bf16*)(regA + 8388608);
  bf16* vT    = (bf16*)(regA + 16777216);
  bf16* obuf  = (bf16*)(regA + 25165824);
  // weights (bf16, pre-transposed), all layers
  bf16* WqkvT = (bf16*)carve(9437184);
  bf16* WoT   = (bf16*)carve(3145728);
  bf16* W1T   = (bf16*)carve(12582912);
  bf16* W2T   = (bf16*)carve(12582912);
  bf16* Wq0h  = (bf16*)carve(524288);
  bf16* Wq0l  = (bf16*)carve(524288);
  bf16* Wk0h  = (bf16*)carve(524288);
  bf16* Wk0l  = (bf16*)carve(524288);
  bf16* peb   = (bf16*)carve(524288);
  bf16* pqwT  = (bf16*)carve(524288);
  bf16* pkwT  = (bf16*)carve(524288);
  bf16* pqb   = (bf16*)carve(524288);
  bf16* pkb   = (bf16*)carve(524288);
  bf16* spe   = (bf16*)carve(4194304);   // bf16 [h][q][k], pre-scaled by INV_SCALE

  dim3 B256(256);
  const float INV_SCALE = 0.08838834764831845f; // 1/sqrt(128)

  // weight transposes / casts: one merged launch for all 512x512, two for W1/W2
  tcast_all<<<dim3(16,16,28),B256,0,stream>>>(Wq,Wk,Wv,Wo,peqw,pekw,
                                              WqkvT,WoT,pqwT,pkwT,Wq0h,Wq0l,Wk0h,Wk0l);
  tcast<<<dim3(64,16,6),B256,0,stream>>>(W1, 1048576, W1T, 1048576, 512, 2048);
  tcast<<<dim3(16,64,6),B256,0,stream>>>(W2, 1048576, W2T, 1048576, 2048, 512);
  init_h<<<17408,B256,0,stream>>>(x, hf, hb, hlo, pe, peb);

  // positional-encoding projections (merged z=2: z=0 -> pqb (peqb), z=1 -> pkb (pekb))
  gemm_bt<EP_BF16,2><<<dim3(32,1,2),B256,0,stream>>>(peb,nullptr,nullptr, pqwT,nullptr,nullptr, 1, 512,512, 512,512,512, peqb,pekb,nullptr, 1.f, pqb,nullptr,nullptr, 4,1, 0,262144,262144);
  // per-head pe scores, bf16, INV_SCALE folded in
  gemm_bt<EP_BF16,2><<<dim3(32,1,8),B256,0,stream>>>(pqb,nullptr,nullptr, pkb,nullptr,nullptr, 1, 512,512, 512,512,64, nullptr,nullptr,nullptr, INV_SCALE, spe,nullptr,nullptr, 4,1, 64,64,262144);

  for (int l=0;l<6;l++){
    const bf16* WQKV = WqkvT + l*786432;
    const float* bql = bq + l*512;
    const float* bkl = bk + l*512;
    const float* bvl = bv + l*512;
    if (l==0){
      // layer 0: q,k from split-precision HILO (merged z=2: z=0 q, z=1 k); QKV computes V only
      gemm_bt<EP_VT,2><<<dim3(512),B256,0,stream>>>(hb,nullptr,nullptr, WQKV+524288,nullptr,nullptr, 1, 512,512, 8192,512,512, nullptr,nullptr,bvl, 1.f, nullptr,nullptr,vT, 4,16, 0,0,0);
      gemm_bt<EP_HILO,2><<<dim3(512,1,2),B256,0,stream>>>(hb,hb,hlo, Wq0h,Wq0l,Wq0h, 3, 512,512, 8192,512,512, bql,bkl,nullptr, 1.f, qb, qlo, nullptr, 4,16, 0,524288,4194304);
      attn_mfma<1><<<dim3(1024),B256,0,stream>>>(qb,qlo,kbuf,klo,vT,spe,obuf);
    } else {
      gemm_bt<EP_QKV,2><<<dim3(1536),B256,0,stream>>>(hb,nullptr,nullptr, WQKV,nullptr,nullptr, 1, 512,512, 8192,1536,512, bql,bkl,bvl, 1.f, qb, kbuf, vT, 12,16, 0,0,0);
      attn_mfma<0><<<dim3(1024),B256,0,stream>>>(qb,qb,kbuf,kbuf,vT,spe,obuf);
    }
    gemm_bt<EP_BF16,2><<<dim3(512),B256,0,stream>>>(obuf,nullptr,nullptr, WoT+l*262144,nullptr,nullptr, 1, 512,512, 8192,512,512, bo+l*512,nullptr,nullptr, 1.f, tmpb,nullptr,nullptr, 4,16, 0,0,0);
    ln_kernel<<<2048,B256,0,stream>>>(tmpb, hf, g1+l*512, bb1+l*512, h1f, h1b);
    gemm_bt<EP_GELU,2><<<dim3(2048),B256,0,stream>>>(h1b,nullptr,nullptr, W1T+l*1048576,nullptr,nullptr, 1, 512,512, 8192,2048,512, fb1+l*2048,nullptr,nullptr, 1.f, gbuf,nullptr,nullptr, 16,16, 0,0,0);
    gemm_bt<EP_BF16,2><<<dim3(512),B256,0,stream>>>(gbuf,nullptr,nullptr, W2T+l*1048576,nullptr,nullptr, 1, 2048,2048, 8192,512,2048, fb2+l*512,nullptr,nullptr, 1.f, tmpb,nullptr,nullptr, 4,16, 0,0,0);
    // last layer: LN2 writes the fp32 h chunk of d_out directly
    ln_kernel<<<2048,B256,0,stream>>>(tmpb, h1f, g2+l*512, bb2+l*512,
                                      (l==5) ? (float*)d_out : hf, hb);
  }
  pe_out<<<16384,B256,0,stream>>>(pe, (float*)d_out, 4194304);
}

// Round 22
// 1130.365 us; speedup vs baseline: 1.0493x; 1.0493x over previous
//
#include <hip/hip_runtime.h>
#include <hip/hip_bf16.h>

typedef __hip_bfloat16 bf16;
typedef short bf16x8 __attribute__((ext_vector_type(8)));
typedef float f32x4 __attribute__((ext_vector_type(4)));

#define DEV static __device__ __forceinline__

DEV f32x4 fzero4(){ f32x4 z; z[0]=0.f; z[1]=0.f; z[2]=0.f; z[3]=0.f; return z; }

DEV float bf2f(bf16 v){
  unsigned int u = ((unsigned int)*(unsigned short*)&v) << 16;
  return *(float*)&u;
}
DEV float bf2s(short s){
  unsigned int u = ((unsigned int)(unsigned short)s) << 16;
  return *(float*)&u;
}

#if __has_builtin(__builtin_amdgcn_rcpf)
DEV float frcp(float x){ return __builtin_amdgcn_rcpf(x); }
#else
DEV float frcp(float x){ float r; asm("v_rcp_f32 %0, %1" : "=v"(r) : "v"(x)); return r; }
#endif

// fast GELU (tanh form): max abs err ~1e-3 vs exact erf GELU; NaN-safe at |x| large
DEV float fast_gelu(float x){
  float u = 0.7978845608028654f * x * (1.f + 0.044715f * x * x);
  float e = __expf(2.f * u);
  float th = 1.f - 2.f * frcp(e + 1.f);   // tanh(u); e=inf -> 1, e=0 -> -1
  return 0.5f * x * (1.f + th);
}

DEV void gl2lds16(const bf16* g, bf16* l){
  __builtin_amdgcn_global_load_lds(
    (const __attribute__((address_space(1))) void*)g,
    (__attribute__((address_space(3))) void*)l, 16, 0, 0);
}

enum { EP_F32=0, EP_BF16=1, EP_GELU=2, EP_HILO=3, EP_QKV=4, EP_VT=5 };

// C[M][N] = sum_p A_p[M][K] * B_p[N][K]^T  (+bias, epilogue variants)
// BM=NMT*32 (128 or 64), BN=128, BK=32, 256 threads (4 waves).
// 1-D grid = nn * (mchunk*8) blocks; xcd = bid&7 owns m-chunk.
// z-dim batches independent problems: azs/bzs/ozs are element strides; when
// bs1 != null and z>0, bs1 replaces bs0 as the bias (EP_BF16 / EP_HILO).
// Double-buffered LDS staging via global_load_lds: one barrier per K-step.
template<int EPI, int NMT>
__global__ __launch_bounds__(256) void gemm_bt(
    const bf16* A0, const bf16* A1, const bf16* A2,
    const bf16* B0, const bf16* B1, const bf16* B2,
    int npass, int lda, int ldb, int M, int N, int K,
    const float* __restrict__ bs0, const float* __restrict__ bs1, const float* __restrict__ bs2,
    float alpha, void* o0, void* o1, void* o2,
    int nn, int mchunk, int azs, int bzs, int ozs)
{
  constexpr int BM = NMT*32;
  __shared__ __align__(16) bf16 As[2][BM*32];
  __shared__ __align__(16) bf16 Bs[2][128*32];
  const int t = threadIdx.x;
  const int lane = t & 63;
  const int w = t >> 6;
  const int wr = w >> 1, wc = w & 1;
  const int bid = blockIdx.x;
  const int xcd = bid & 7;
  const int idx = bid >> 3;
  const int qm = idx / nn;
  const int mb = xcd*mchunk + qm;
  const int nb = idx - qm*nn;
  const int m0 = mb*BM, n0 = nb*128;
  const int l15 = lane & 15, l4 = lane >> 4;
  const int grow = (lane >> 2);       // 0..15 within a 16-row stripe
  const int gcol = (lane & 3) * 8;    // 0,8,16,24
  const int z = blockIdx.z;
  if (azs){ A0 += (size_t)z*azs; if(A1) A1 += (size_t)z*azs; if(A2) A2 += (size_t)z*azs; }
  if (bzs){ B0 += (size_t)z*bzs; if(B1) B1 += (size_t)z*bzs; if(B2) B2 += (size_t)z*bzs; }

  auto Aof = [&](int p){ return (p==0)?A0:((p==1)?A1:A2); };
  auto Bof = [&](int p){ return (p==0)?B0:((p==1)?B1:B2); };

  auto stageAB = [&](int cb, const bf16* Ag, const bf16* Bg, int k0){
    if constexpr (NMT==4){
      #pragma unroll
      for (int q=0;q<2;q++){
        int row = w*32 + q*16 + grow;
        gl2lds16(Ag + (size_t)(m0+row)*lda + k0 + gcol, As[cb] + (w*32+q*16)*32);
        gl2lds16(Bg + (size_t)(n0+row)*ldb + k0 + gcol, Bs[cb] + (w*32+q*16)*32);
      }
    } else {
      int rA = w*16 + grow;
      gl2lds16(Ag + (size_t)(m0+rA)*lda + k0 + gcol, As[cb] + w*16*32);
      #pragma unroll
      for (int sb=0;sb<2;sb++){
        int rB = (2*w+sb)*16 + grow;
        gl2lds16(Bg + (size_t)(n0+rB)*ldb + k0 + gcol, Bs[cb] + (2*w+sb)*16*32);
      }
    }
  };

  f32x4 acc[NMT][4];
  #pragma unroll
  for (int i=0;i<NMT;i++)
    #pragma unroll
    for (int j=0;j<4;j++) acc[i][j] = fzero4();

  int cur = 0;
  stageAB(0, A0, B0, 0);
  for (int p=0;p<npass;p++){
    for (int k0=0;k0<K;k0+=32){
      __syncthreads();            // buf[cur] staged; prev reads done
      int kn = k0 + 32;
      if (kn < K)            stageAB(cur^1, Aof(p), Bof(p), kn);
      else if (p+1 < npass)  stageAB(cur^1, Aof(p+1), Bof(p+1), 0);
      bf16x8 af[NMT], bfv[4];
      #pragma unroll
      for (int mt=0;mt<NMT;mt++) af[mt] = *(const bf16x8*)(As[cur] + (wr*(NMT*16)+mt*16+l15)*32 + 8*l4);
      #pragma unroll
      for (int nt=0;nt<4;nt++) bfv[nt] = *(const bf16x8*)(Bs[cur] + (wc*64+nt*16+l15)*32 + 8*l4);
      #pragma unroll
      for (int mt=0;mt<NMT;mt++)
        #pragma unroll
        for (int nt=0;nt<4;nt++)
          acc[mt][nt] = __builtin_amdgcn_mfma_f32_16x16x32_bf16(af[mt], bfv[nt], acc[mt][nt], 0, 0, 0);
      cur ^= 1;
    }
  }

  const float* bb = (z && bs1) ? bs1 : bs0;

  #pragma unroll
  for (int mt=0;mt<NMT;mt++){
    #pragma unroll
    for (int nt=0;nt<4;nt++){
      const int crow = m0 + wr*(NMT*16) + mt*16 + l4*4;
      const int ccol = n0 + wc*64 + nt*16 + l15;
      #pragma unroll
      for (int j=0;j<4;j++){
        float v = acc[mt][nt][j];
        int r = crow + j;
        if (EPI==EP_F32){
          float b = bb ? bb[ccol] : 0.f;
          ((float*)o0)[(size_t)r*N + ccol] = alpha*v + b;
        } else if (EPI==EP_BF16){
          float b = bb ? bb[ccol] : 0.f;
          ((bf16*)o0 + (size_t)z*ozs)[(size_t)r*N + ccol] = __float2bfloat16(alpha*v + b);
        } else if (EPI==EP_GELU){
          float xx = v + bb[ccol];
          ((bf16*)o0)[(size_t)r*N + ccol] = __float2bfloat16(fast_gelu(xx));
        } else if (EPI==EP_HILO){
          float xx = (v + bb[ccol]) * alpha;
          bf16 hi = __float2bfloat16(xx);
          ((bf16*)o0 + (size_t)z*ozs)[(size_t)r*N + ccol] = hi;
          ((bf16*)o1 + (size_t)z*ozs)[(size_t)r*N + ccol] = __float2bfloat16(xx - bf2f(hi));
        } else if (EPI==EP_VT){ // v only, transposed [b,h,d,s]; N=512
          int d = ccol;
          int bb2 = r >> 9, s2 = r & 511;
          int hh = d >> 6, dd = d & 63;
          ((bf16*)o2)[(size_t)(((bb2*8)+hh)*64 + dd)*512 + s2] = __float2bfloat16(v + bs2[d]);
        } else { // EP_QKV : N=1536 concat q|k|v; q scaled by alpha; v transposed [b,h,d,s]
          int n = ccol;
          if (n < 512){
            ((bf16*)o0)[(size_t)r*512 + n] = __float2bfloat16((v + bs0[n]) * alpha);
          } else if (n < 1024){
            ((bf16*)o1)[(size_t)r*512 + (n-512)] = __float2bfloat16(v + bs1[n-512]);
          } else {
            int d = n - 1024;
            int bb2 = r >> 9, s2 = r & 511;
            int hh = d >> 6, dd = d & 63;
            ((bf16*)o2)[(size_t)(((bb2*8)+hh)*64 + dd)*512 + s2] = __float2bfloat16(v + bs2[d]);
          }
        }
      }
    }
  }
}

// MFMA flash attention — round-6/15 form (measured best: ~50 us/dispatch).
// 256 thr (4 waves x 16 q-rows), KVBLK=64, single-buffered K/V in LDS (XOR-swizzled),
// SPE (bf16, pre-scaled by 1/sqrt(2dk)) added after the QK MFMAs; __expf softmax;
// unconditional online rescale. 1D grid 1024: h = bid&7 (pins head to XCD).
template<int SPLIT>
__global__ __launch_bounds__(256) void attn_mfma(
  const bf16* __restrict__ Q, const bf16* __restrict__ Qlo,
  const bf16* __restrict__ Kh, const bf16* __restrict__ Klo,
  const bf16* __restrict__ VT, const bf16* __restrict__ SPE,
  bf16* __restrict__ O)
{
  __shared__ __align__(16) bf16 K_lds[64*64];
  __shared__ __align__(16) bf16 V_lds[64*64];
  __shared__ __align__(16) bf16 Klo_lds[SPLIT ? 64*64 : 8];
  __shared__ __align__(16) bf16 P_lds[4][16*64];
  const int t = threadIdx.x;
  const int lane = t & 63, w = t >> 6;
  const int l15 = lane & 15, l4 = lane >> 4;
  const int bid = blockIdx.x;
  const int h = bid & 7;
  const int s2 = bid >> 3;
  const int b = s2 >> 3, qblk = s2 & 7;
  const int q0 = qblk*64 + w*16;
  const float inv_scale = 0.08838834764831845f; // 1/sqrt(128)
  const int xorv = (l15 & 7) << 3;

  bf16x8 qf[2], qflo[2];
  #pragma unroll
  for (int kst=0;kst<2;kst++){
    qf[kst] = *(const bf16x8*)(Q + (size_t)(b*512 + q0 + l15)*512 + h*64 + kst*32 + 8*l4);
    if (SPLIT) qflo[kst] = *(const bf16x8*)(Qlo + (size_t)(b*512 + q0 + l15)*512 + h*64 + kst*32 + 8*l4);
  }
  f32x4 accO[4];
  #pragma unroll
  for (int dt=0;dt<4;dt++) accO[dt] = fzero4();
  float mrow[4], lrow[4];
  #pragma unroll
  for (int j=0;j<4;j++){ mrow[j] = -1e30f; lrow[j] = 0.f; }

  const bf16* spe_h = SPE + (size_t)h*262144;
  const bf16* vbase = VT + (size_t)((b*8)+h)*32768;

  for (int n0=0;n0<512;n0+=64){
    // stage K (and Klo), V^T tiles: wave w covers rows [w*16, w*16+16)
    #pragma unroll
    for (int st=0;st<2;st++){
      int rl = w*16 + st*8 + (lane>>3);          // tile-local row 0..63
      int jj = (lane&7) ^ (rl&7);                // pre-swizzled 16B-chunk col
      gl2lds16(Kh + (size_t)(b*512 + n0 + rl)*512 + h*64 + jj*8, K_lds + (w*16+st*8)*64);
      if (SPLIT)
        gl2lds16(Klo + (size_t)(b*512 + n0 + rl)*512 + h*64 + jj*8, Klo_lds + (w*16+st*8)*64);
      gl2lds16(vbase + (size_t)rl*512 + n0 + jj*8, V_lds + (w*16+st*8)*64);
    }
    __syncthreads();

    f32x4 sc[4];
    #pragma unroll
    for (int c=0;c<4;c++) sc[c] = fzero4();
    #pragma unroll
    for (int c=0;c<4;c++){
      const int rr = c*16 + l15;
      #pragma unroll
      for (int kst=0;kst<2;kst++){
        bf16x8 kf = *(const bf16x8*)(K_lds + rr*64 + ((kst*32 + 8*l4) ^ xorv));
        sc[c] = __builtin_amdgcn_mfma_f32_16x16x32_bf16(qf[kst], kf, sc[c], 0,0,0);
        if (SPLIT){
          sc[c] = __builtin_amdgcn_mfma_f32_16x16x32_bf16(qflo[kst], kf, sc[c], 0,0,0);
          bf16x8 kfl = *(const bf16x8*)(Klo_lds + rr*64 + ((kst*32 + 8*l4) ^ xorv));
          sc[c] = __builtin_amdgcn_mfma_f32_16x16x32_bf16(qf[kst], kfl, sc[c], 0,0,0);
        }
      }
    }
    float sv[4][4];
    #pragma unroll
    for (int c=0;c<4;c++)
      #pragma unroll
      for (int j=0;j<4;j++){
        int qr = q0 + l4*4 + j;
        sv[c][j] = sc[c][j]*inv_scale + bf2f(spe_h[(size_t)qr*512 + n0 + c*16 + l15]);
      }
    float fac[4];
    #pragma unroll
    for (int j=0;j<4;j++){
      float m2 = fmaxf(fmaxf(sv[0][j],sv[1][j]), fmaxf(sv[2][j],sv[3][j]));
      m2 = fmaxf(m2, __shfl_xor(m2,1));
      m2 = fmaxf(m2, __shfl_xor(m2,2));
      m2 = fmaxf(m2, __shfl_xor(m2,4));
      m2 = fmaxf(m2, __shfl_xor(m2,8));
      float mn = fmaxf(mrow[j], m2);
      fac[j] = __expf(mrow[j] - mn);
      mrow[j] = mn;
    }
    #pragma unroll
    for (int j=0;j<4;j++){
      int row = l4*4 + j;
      float ts = 0.f;
      #pragma unroll
      for (int c=0;c<4;c++){
        float pv = __expf(sv[c][j] - mrow[j]);
        ts += pv;
        P_lds[w][row*64 + ((c*16 + l15) ^ ((row&7)<<3))] = __float2bfloat16(pv);
      }
      ts += __shfl_xor(ts,1); ts += __shfl_xor(ts,2);
      ts += __shfl_xor(ts,4); ts += __shfl_xor(ts,8);
      lrow[j] = lrow[j]*fac[j] + ts;
      #pragma unroll
      for (int dt=0;dt<4;dt++) accO[dt][j] *= fac[j];
    }
    #pragma unroll
    for (int kv=0;kv<2;kv++){
      bf16x8 pf = *(const bf16x8*)(P_lds[w] + l15*64 + ((kv*32 + 8*l4) ^ xorv));
      #pragma unroll
      for (int dt=0;dt<4;dt++){
        const int d = dt*16 + l15;
        bf16x8 vf = *(const bf16x8*)(V_lds + d*64 + ((kv*32 + 8*l4) ^ xorv));
        accO[dt] = __builtin_amdgcn_mfma_f32_16x16x32_bf16(pf, vf, accO[dt], 0,0,0);
      }
    }
    __syncthreads();
  }
  float li[4];
  #pragma unroll
  for (int j=0;j<4;j++) li[j] = frcp(lrow[j]);
  #pragma unroll
  for (int dt=0;dt<4;dt++)
    #pragma unroll
    for (int j=0;j<4;j++){
      float v = accO[dt][j] * li[j];
      int r = q0 + l4*4 + j;
      O[(size_t)(b*512+r)*512 + h*64 + dt*16 + l15] = __float2bfloat16(v);
    }
}

// LayerNorm(tmp(bf16) + resid(f32)) -> outf (fp32), outb (bf16). One wave per row.
__global__ __launch_bounds__(256) void ln_kernel(
  const bf16* __restrict__ tmp, const float* __restrict__ resid,
  const float* __restrict__ g, const float* __restrict__ bta,
  float* __restrict__ outf, bf16* __restrict__ outb)
{
  const int row = blockIdx.x*4 + (threadIdx.x>>6);
  const int lane = threadIdx.x & 63;
  const size_t base = (size_t)row*512 + lane*8;
  bf16x8 a = *(const bf16x8*)(tmp+base);
  float4 r0 = *(const float4*)(resid+base), r1 = *(const float4*)(resid+base+4);
  float x[8];
  x[0]=bf2s(a[0])+r0.x; x[1]=bf2s(a[1])+r0.y;
  x[2]=bf2s(a[2])+r0.z; x[3]=bf2s(a[3])+r0.w;
  x[4]=bf2s(a[4])+r1.x; x[5]=bf2s(a[5])+r1.y;
  x[6]=bf2s(a[6])+r1.z; x[7]=bf2s(a[7])+r1.w;
  float s=0.f, sq=0.f;
  #pragma unroll
  for (int i=0;i<8;i++){ s += x[i]; sq += x[i]*x[i]; }
  #pragma unroll
  for (int d=1; d<64; d<<=1){ s += __shfl_xor(s,d); sq += __shfl_xor(sq,d); }
  float mean = s*(1.f/512.f);
  float var = sq*(1.f/512.f) - mean*mean;
  float rr = rsqrtf(var + 1e-6f);
  #pragma unroll
  for (int i=0;i<8;i++){
    int d = lane*8 + i;
    float y = (x[i]-mean)*rr*g[d] + bta[d];
    outf[base+i] = y;
    outb[base+i] = __float2bfloat16(y);
  }
}

// merged transpose+cast for ALL 512x512 weights. grid (16,16,28):
//  z<24: which=z&3 in {Wq,Wk,Wv,Wo}, l=z>>2 -> WqkvT/WoT
//  z=24: peqw->pqwT ; z=25: pekw->pkwT
//  z=26: Wq(l0)->Wq0h+Wq0l ; z=27: Wk(l0)->Wk0h+Wk0l  (hi/lo split)
__global__ __launch_bounds__(256) void tcast_all(
  const float* __restrict__ Wq, const float* __restrict__ Wk,
  const float* __restrict__ Wv, const float* __restrict__ Wo,
  const float* __restrict__ peqw, const float* __restrict__ pekw,
  bf16* __restrict__ WqkvT, bf16* __restrict__ WoT,
  bf16* __restrict__ pqwT, bf16* __restrict__ pkwT,
  bf16* __restrict__ Wq0h, bf16* __restrict__ Wq0l,
  bf16* __restrict__ Wk0h, bf16* __restrict__ Wk0l)
{
  __shared__ float tile[32][33];
  const int z = blockIdx.z;
  const float* src; bf16* dst; bf16* dlo = nullptr;
  if (z < 24){
    int which = z & 3, l = z >> 2;
    src = ((which==0)?Wq:(which==1)?Wk:(which==2)?Wv:Wo) + (size_t)l*262144;
    dst = (which<3) ? (WqkvT + (size_t)l*786432 + (size_t)which*262144)
                    : (WoT + (size_t)l*262144);
  } else if (z==24){ src=peqw; dst=pqwT; }
  else if (z==25){ src=pekw; dst=pkwT; }
  else if (z==26){ src=Wq; dst=Wq0h; dlo=Wq0l; }
  else           { src=Wk; dst=Wk0h; dlo=Wk0l; }

  const int tx = threadIdx.x & 31, ty = threadIdx.x >> 5;
  const int r0 = blockIdx.y*32, c0 = blockIdx.x*32;
  #pragma unroll
  for (int p=0;p<4;p++)
    tile[ty+8*p][tx] = src[(size_t)(r0+ty+8*p)*512 + c0+tx];
  __syncthreads();
  #pragma unroll
  for (int p=0;p<4;p++){
    float v = tile[tx][ty+8*p];
    bf16 hi = __float2bfloat16(v);
    dst[(size_t)(c0+ty+8*p)*512 + r0+tx] = hi;
    if (dlo) dlo[(size_t)(c0+ty+8*p)*512 + r0+tx] = __float2bfloat16(v - bf2f(hi));
  }
}

// transpose + cast fp32 [R][C] -> bf16 [C][R], per grid.z slice (W1/W2 only)
__global__ __launch_bounds__(256) void tcast(
  const float* __restrict__ src, int srcStride,
  bf16* __restrict__ dst, int dstStride,
  int R, int C)
{
  __shared__ float tile[32][33];
  const int z = blockIdx.z;
  src += (size_t)z*srcStride;
  dst += (size_t)z*dstStride;
  const int tx = threadIdx.x & 31, ty = threadIdx.x >> 5;
  const int r0 = blockIdx.y*32, c0 = blockIdx.x*32;
  #pragma unroll
  for (int p=0;p<4;p++)
    tile[ty+8*p][tx] = src[(size_t)(r0+ty+8*p)*C + c0+tx];
  __syncthreads();
  #pragma unroll
  for (int p=0;p<4;p++){
    float v = tile[tx][ty+8*p];
    dst[(size_t)(c0+ty+8*p)*R + r0+tx] = __float2bfloat16(v);
  }
}

// h init (scale + bf16 hi/lo split) fused with pe bf16 cast.
// grid covers 4194304 + 262144 elements.
__global__ void init_h(const float* __restrict__ x, float* __restrict__ hf,
                       bf16* __restrict__ hb, bf16* __restrict__ hlo,
                       const float* __restrict__ pe, bf16* __restrict__ peb){
  int i = blockIdx.x*blockDim.x + threadIdx.x;
  if (i < 4194304){
    float v = x[i]*22.627416997969522f;   // sqrt(512)
    hf[i] = v;
    bf16 hi = __float2bfloat16(v);
    hb[i] = hi;
    hlo[i] = __float2bfloat16(v - bf2f(hi));
  } else if (i < 4456448){
    int j = i - 4194304;
    peb[j] = __float2bfloat16(pe[j]);
  }
}

// pe broadcast chunk of d_out (h chunk is written directly by the last ln_kernel)
__global__ void pe_out(const float* __restrict__ pe, float* __restrict__ out, int n1){
  int i = blockIdx.x*blockDim.x + threadIdx.x;
  if (i < n1) out[n1 + i] = pe[i & 262143];
}

extern "C" void kernel_launch(void* const* d_in, const int* in_sizes, int n_in,
                              void* d_out, int out_size, void* d_ws, size_t ws_size,
                              hipStream_t stream)
{
  const float* x    = (const float*)d_in[0];
  const float* pe   = (const float*)d_in[1];
  const float* peqw = (const float*)d_in[2];
  const float* peqb = (const float*)d_in[3];
  const float* pekw = (const float*)d_in[4];
  const float* pekb = (const float*)d_in[5];
  const float* Wq   = (const float*)d_in[6];
  const float* bq   = (const float*)d_in[7];
  const float* Wk   = (const float*)d_in[8];
  const float* bk   = (const float*)d_in[9];
  const float* Wv   = (const float*)d_in[10];
  const float* bv   = (const float*)d_in[11];
  const float* Wo   = (const float*)d_in[12];
  const float* bo   = (const float*)d_in[13];
  const float* g1   = (const float*)d_in[14];
  const float* bb1  = (const float*)d_in[15];
  const float* W1   = (const float*)d_in[16];
  const float* fb1  = (const float*)d_in[17];
  const float* W2   = (const float*)d_in[18];
  const float* fb2  = (const float*)d_in[19];
  const float* g2   = (const float*)d_in[20];
  const float* bb2  = (const float*)d_in[21];

  char* wp = (char*)d_ws;
  auto carve = [&](size_t bytes)->void*{ void* r = (void*)wp; wp += (bytes + 255) & ~(size_t)255; return r; };
  // persistent fp32 streams
  float* hf   = (float*)carve(16777216);
  float* h1f  = (float*)carve(16777216);
  // region B: tmpb (bf16 8192x512) overlaps qlo|klo (bf16, layer0-attn only)
  char*  regB = (char*)carve(16777216);
  bf16*  tmpb = (bf16*)regB;
  bf16*  qlo  = (bf16*)regB;
  bf16*  klo  = (bf16*)(regB + 8388608);
  // bf16 streams
  bf16* hb    = (bf16*)carve(8388608);
  bf16* hlo   = (bf16*)carve(8388608);
  bf16* h1b   = (bf16*)carve(8388608);
  // region A: gbuf (bf16 8192x2048) overlaps qb|kbuf|vT|obuf (attn phase)
  char* regA  = (char*)carve(33554432);
  bf16* gbuf  = (bf16*)regA;
  bf16* qb    = (bf16*)regA;
  bf16* kbuf  = (bf16*)(regA + 8388608);
  bf16* vT    = (bf16*)(regA + 16777216);
  bf16* obuf  = (bf16*)(regA + 25165824);
  // weights (bf16, pre-transposed), all layers
  bf16* WqkvT = (bf16*)carve(9437184);
  bf16* WoT   = (bf16*)carve(3145728);
  bf16* W1T   = (bf16*)carve(12582912);
  bf16* W2T   = (bf16*)carve(12582912);
  bf16* Wq0h  = (bf16*)carve(524288);
  bf16* Wq0l  = (bf16*)carve(524288);
  bf16* Wk0h  = (bf16*)carve(524288);
  bf16* Wk0l  = (bf16*)carve(524288);
  bf16* peb   = (bf16*)carve(524288);
  bf16* pqwT  = (bf16*)carve(524288);
  bf16* pkwT  = (bf16*)carve(524288);
  bf16* pqb   = (bf16*)carve(524288);
  bf16* pkb   = (bf16*)carve(524288);
  bf16* spe   = (bf16*)carve(4194304);   // bf16 [h][q][k], pre-scaled by INV_SCALE

  dim3 B256(256);
  const float INV_SCALE = 0.08838834764831845f; // 1/sqrt(128)

  // weight transposes / casts: one merged launch for all 512x512, two for W1/W2
  tcast_all<<<dim3(16,16,28),B256,0,stream>>>(Wq,Wk,Wv,Wo,peqw,pekw,
                                              WqkvT,WoT,pqwT,pkwT,Wq0h,Wq0l,Wk0h,Wk0l);
  tcast<<<dim3(64,16,6),B256,0,stream>>>(W1, 1048576, W1T, 1048576, 512, 2048);
  tcast<<<dim3(16,64,6),B256,0,stream>>>(W2, 1048576, W2T, 1048576, 2048, 512);
  init_h<<<17408,B256,0,stream>>>(x, hf, hb, hlo, pe, peb);

  // positional-encoding projections (merged z=2: z=0 -> pqb (peqb), z=1 -> pkb (pekb))
  gemm_bt<EP_BF16,2><<<dim3(32,1,2),B256,0,stream>>>(peb,nullptr,nullptr, pqwT,nullptr,nullptr, 1, 512,512, 512,512,512, peqb,pekb,nullptr, 1.f, pqb,nullptr,nullptr, 4,1, 0,262144,262144);
  // per-head pe scores, bf16, INV_SCALE folded in
  gemm_bt<EP_BF16,2><<<dim3(32,1,8),B256,0,stream>>>(pqb,nullptr,nullptr, pkb,nullptr,nullptr, 1, 512,512, 512,512,64, nullptr,nullptr,nullptr, INV_SCALE, spe,nullptr,nullptr, 4,1, 64,64,262144);

  for (int l=0;l<6;l++){
    const bf16* WQKV = WqkvT + l*786432;
    const float* bql = bq + l*512;
    const float* bkl = bk + l*512;
    const float* bvl = bv + l*512;
    if (l==0){
      // layer 0: q,k from split-precision HILO (merged z=2: z=0 q, z=1 k); QKV computes V only
      gemm_bt<EP_VT,2><<<dim3(512),B256,0,stream>>>(hb,nullptr,nullptr, WQKV+524288,nullptr,nullptr, 1, 512,512, 8192,512,512, nullptr,nullptr,bvl, 1.f, nullptr,nullptr,vT, 4,16, 0,0,0);
      gemm_bt<EP_HILO,2><<<dim3(512,1,2),B256,0,stream>>>(hb,hb,hlo, Wq0h,Wq0l,Wq0h, 3, 512,512, 8192,512,512, bql,bkl,nullptr, 1.f, qb, qlo, nullptr, 4,16, 0,524288,4194304);
      attn_mfma<1><<<dim3(1024),B256,0,stream>>>(qb,qlo,kbuf,klo,vT,spe,obuf);
    } else {
      gemm_bt<EP_QKV,4><<<dim3(768),B256,0,stream>>>(hb,nullptr,nullptr, WQKV,nullptr,nullptr, 1, 512,512, 8192,1536,512, bql,bkl,bvl, 1.f, qb, kbuf, vT, 12,8, 0,0,0);
      attn_mfma<0><<<dim3(1024),B256,0,stream>>>(qb,qb,kbuf,kbuf,vT,spe,obuf);
    }
    gemm_bt<EP_BF16,2><<<dim3(512),B256,0,stream>>>(obuf,nullptr,nullptr, WoT+l*262144,nullptr,nullptr, 1, 512,512, 8192,512,512, bo+l*512,nullptr,nullptr, 1.f, tmpb,nullptr,nullptr, 4,16, 0,0,0);
    ln_kernel<<<2048,B256,0,stream>>>(tmpb, hf, g1+l*512, bb1+l*512, h1f, h1b);
    gemm_bt<EP_GELU,2><<<dim3(2048),B256,0,stream>>>(h1b,nullptr,nullptr, W1T+l*1048576,nullptr,nullptr, 1, 512,512, 8192,2048,512, fb1+l*2048,nullptr,nullptr, 1.f, gbuf,nullptr,nullptr, 16,16, 0,0,0);
    gemm_bt<EP_BF16,2><<<dim3(512),B256,0,stream>>>(gbuf,nullptr,nullptr, W2T+l*1048576,nullptr,nullptr, 1, 2048,2048, 8192,512,2048, fb2+l*512,nullptr,nullptr, 1.f, tmpb,nullptr,nullptr, 4,16, 0,0,0);
    // last layer: LN2 writes the fp32 h chunk of d_out directly
    ln_kernel<<<2048,B256,0,stream>>>(tmpb, h1f, g2+l*512, bb2+l*512,
                                      (l==5) ? (float*)d_out : hf, hb);
  }
  pe_out<<<16384,B256,0,stream>>>(pe, (float*)d_out, 4194304);
}